// Round 4
// baseline (440.647 us; speedup 1.0000x reference)
//
#include <hip/hip_runtime.h>

#define S_LEN 2048

typedef __attribute__((ext_vector_type(8))) short bf16x8;
typedef __attribute__((ext_vector_type(4))) float f32x4;
typedef __attribute__((ext_vector_type(4))) unsigned int u32x4;
typedef unsigned long long u64;
typedef unsigned int u32;
typedef unsigned short u16;

// may_alias variants for LDS round-trips (u64 store / bf16x8 load of the same
// bytes): without these, TBAA lets the scheduler reorder the ds_read above the
// ds_write (round-3 NaN failure).
typedef bf16x8 __attribute__((may_alias)) bf16x8a;
typedef u64 __attribute__((may_alias)) u64a;

#define MFMA16 __builtin_amdgcn_mfma_f32_16x16x32_bf16

// single-instruction pack: a -> low16, b -> high16 (RNE)
__device__ __forceinline__ u32 cvtpk(float a, float b) {
  u32 r;
  asm("v_cvt_pk_bf16_f32 %0, %1, %2" : "=v"(r) : "v"(a), "v"(b));
  return r;
}
// raw hardware 2^x (avoid OCML wrapper ops around v_exp_f32)
__device__ __forceinline__ float exp2hw(float x) {
  float r;
  asm("v_exp_f32 %0, %1" : "=v"(r) : "v"(x));
  return r;
}

// 64x64 bf16 tile, 128B rows, 8 x 16B blocks/row, block swizzled by xor(row&7).
__device__ __forceinline__ bf16x8 ldfrag(const u16* base, int row, int blk) {
  const char* p = (const char*)base + (((row << 3) + (blk ^ (row & 7))) << 4);
  return *(const bf16x8a*)p;
}

// async global->LDS, 16B per lane; LDS dst = wave-uniform base + lane*16.
__device__ __forceinline__ void gload16(const u16* g, u16* l) {
  __builtin_amdgcn_global_load_lds((const __attribute__((address_space(1))) void*)g,
                                   (__attribute__((address_space(3))) void*)l, 16, 0, 0);
}

// ---------------------------------------------------------------------------
// Pre-pass: one-time conversions into workspace (unchanged).
// ---------------------------------------------------------------------------
__global__ __launch_bounds__(256) void prep_kernel(
    const float* __restrict__ gk, const float* __restrict__ gv,
    const int* __restrict__ gmask,
    u16* __restrict__ wsK, u16* __restrict__ wsV,
    u16* __restrict__ wsM, float* __restrict__ wsVs) {
  __shared__ float tile[64 * 65];   // V^T staged: tile[d*65 + k] (65-stride: bank-free)
  __shared__ float sred[2][256];    // Vsum partials
  const int bid = blockIdx.x, t = threadIdx.x;
  if (bid < 2048) {
    const int bh = bid >> 5, kt = bid & 31;
    const float* kg = gk + ((size_t)bh << 17) + ((size_t)kt << 12);
    const float* vg = gv + ((size_t)bh << 17) + ((size_t)kt << 12);
    u16* outK = wsK + ((size_t)bid << 12);
    u16* outV = wsV + ((size_t)bid << 12);
    const int r0 = t >> 4, c4 = t & 15;
#pragma unroll
    for (int i = 0; i < 4; ++i) {
      const int row = r0 + (i << 4);  // k index
      const float4 f = *(const float4*)(vg + (row << 6) + (c4 << 2));
      float* p = tile + row;
      p[((c4 << 2) + 0) * 65] = f.x;
      p[((c4 << 2) + 1) * 65] = f.y;
      p[((c4 << 2) + 2) * 65] = f.z;
      p[((c4 << 2) + 3) * 65] = f.w;
    }
#pragma unroll
    for (int i = 0; i < 2; ++i) {
      const int n = t + (i << 8);
      const int row = n >> 3, cb = (n & 7) ^ (row & 7);
      const float4 A = *(const float4*)(kg + (row << 6) + (cb << 3));
      const float4 B = *(const float4*)(kg + (row << 6) + (cb << 3) + 4);
      u32x4 w;
      w.x = cvtpk(A.x, A.y); w.y = cvtpk(A.z, A.w);
      w.z = cvtpk(B.x, B.y); w.w = cvtpk(B.z, B.w);
      *(u32x4*)(outK + ((size_t)n << 3)) = w;
    }
    __syncthreads();
#pragma unroll
    for (int i = 0; i < 2; ++i) {
      const int n = t + (i << 8);
      const int d = n >> 3, cb = (n & 7) ^ (d & 7);
      const float* src = tile + d * 65 + (cb << 3);
      float e[8], s = 0.f;
#pragma unroll
      for (int j = 0; j < 8; ++j) { e[j] = src[j]; s += e[j]; }
      sred[i][t] = s;
      u32x4 w;
      w.x = cvtpk(e[0], e[1]); w.y = cvtpk(e[2], e[3]);
      w.z = cvtpk(e[4], e[5]); w.w = cvtpk(e[6], e[7]);
      *(u32x4*)(outV + ((size_t)n << 3)) = w;
    }
    __syncthreads();
    if (t < 64) {
      const float* s8 = (t < 32) ? &sred[0][t << 3] : &sred[1][(t - 32) << 3];
      const float s = ((s8[0] + s8[1]) + (s8[2] + s8[3])) +
                      ((s8[4] + s8[5]) + (s8[6] + s8[7]));
      atomicAdd(&wsVs[(bh << 6) + t], s);
    }
  } else {
    const size_t base = ((size_t)(bid - 2048) << 12) + ((size_t)t << 4);
    int4 m[4];
#pragma unroll
    for (int i = 0; i < 4; ++i) m[i] = *(const int4*)(gmask + base + (i << 2));
    u32x4 w0, w1;
    w0.x = (m[0].x ? 0xFFFFu : 0u) | (m[0].y ? 0xFFFF0000u : 0u);
    w0.y = (m[0].z ? 0xFFFFu : 0u) | (m[0].w ? 0xFFFF0000u : 0u);
    w0.z = (m[1].x ? 0xFFFFu : 0u) | (m[1].y ? 0xFFFF0000u : 0u);
    w0.w = (m[1].z ? 0xFFFFu : 0u) | (m[1].w ? 0xFFFF0000u : 0u);
    w1.x = (m[2].x ? 0xFFFFu : 0u) | (m[2].y ? 0xFFFF0000u : 0u);
    w1.y = (m[2].z ? 0xFFFFu : 0u) | (m[2].w ? 0xFFFF0000u : 0u);
    w1.z = (m[3].x ? 0xFFFFu : 0u) | (m[3].y ? 0xFFFF0000u : 0u);
    w1.w = (m[3].z ? 0xFFFFu : 0u) | (m[3].w ? 0xFFFF0000u : 0u);
    *(u32x4*)(wsM + base) = w0;
    *(u32x4*)(wsM + base + 8) = w1;
  }
}

// ---------------------------------------------------------------------------
// Main kernel. One block = one (b*h, 128-row q-tile); 1024 blocks, 4 waves.
// Each wave owns 32 q-columns (2 groups of 16): K/V LDS fragments are reused
// across both groups -> LDS bytes per MFMA drop 1.8x vs 16-col waves.
// out = ln2*A + (1e9 - lse)*Bm - 1e9*Vsum
// W is a wave-private 2KB LDS chunk (32q x 32k, swizzled), reused per k-half:
//   QK tr0,1 -> PV ks=0 -> QK tr2,3 -> PV ks=1
// Same-wave DS ops are in-order in HW; compile-time fences + may_alias types
// keep the compiler from reordering the W round-trip (round-3 lesson).
// ---------------------------------------------------------------------------
__global__ __launch_bounds__(256, 4) void attn_kernel(
    const float* __restrict__ gq, const u16* __restrict__ wsK,
    const u16* __restrict__ wsV, const u16* __restrict__ wsM,
    const float* __restrict__ wsVs, float* __restrict__ gout) {
  __shared__ __align__(16) u16 sK[2][4096];   // 16 KB double-buffered K tile
  __shared__ __align__(16) u16 sV[2][4096];   // 16 KB double-buffered V^T tile
  __shared__ __align__(16) u16 sW[4096];      // 8 KB: 4 x 2KB wave-private W chunks

  const int t = threadIdx.x;
  const int wv = t >> 6;
  const int lane = t & 63;
  const int c = lane & 15;
  const int quad = lane >> 4;

  const int bx = blockIdx.x;
  const int bh = bx & 63;            // consecutive blocks share q0 -> mask L3 locality
  const int q0 = (bx >> 6) << 7;     // 128-row q-tiles

  const float* qg = gq + ((size_t)bh << 17) + ((size_t)q0 << 6);
  const u16* srcK = wsK + ((size_t)bh << 17) + (t << 3);
  const u16* srcV = wsV + ((size_t)bh << 17) + (t << 3);
  const int qrow0 = q0 + (wv << 5) + c;          // group 0 row; group 1 = +16
  const u16* mrow0 = wsM + ((size_t)qrow0 << 11) + (quad << 3);
  const u16* mrow1 = mrow0 + ((size_t)16 << 11);
  u16* const wbase = sW + (wv << 10);            // 2KB wave-private W chunk

  // ---- Q fragments direct from global (once per block), scaled by 0.125*log2e
  const float qs = 0.1803368801111204f;
  bf16x8 qf[2][2];
#pragma unroll
  for (int g = 0; g < 2; ++g)
#pragma unroll
    for (int s = 0; s < 2; ++s) {
      const float* qp = qg + (((wv << 5) + (g << 4) + c) << 6) + (s << 5) + (quad << 3);
      const float4 a = *(const float4*)qp;
      const float4 b = *(const float4*)(qp + 4);
      u32x4 w;
      w.x = cvtpk(a.x * qs, a.y * qs); w.y = cvtpk(a.z * qs, a.w * qs);
      w.z = cvtpk(b.x * qs, b.y * qs); w.w = cvtpk(b.z * qs, b.w * qs);
      qf[g][s] = __builtin_bit_cast(bf16x8, w);
    }

  f32x4 accA0[4], accB0[4], accA1[4], accB1[4];
#pragma unroll
  for (int mt = 0; mt < 4; ++mt) {
    const f32x4 z = {0.f, 0.f, 0.f, 0.f};
    accA0[mt] = z; accB0[mt] = z; accA1[mt] = z; accB1[mt] = z;
  }
  float lac[2] = {0.f, 0.f};

#define STAGE(kt_, buf_) do {                                        \
    const u16* sk_ = srcK + ((kt_) << 12);                           \
    const u16* sv_ = srcV + ((kt_) << 12);                           \
    u16* dk_ = &sK[buf_][wv << 9];                                   \
    u16* dv_ = &sV[buf_][wv << 9];                                   \
    gload16(sk_, dk_);                                               \
    gload16(sk_ + 2048, dk_ + 2048);                                 \
    gload16(sv_, dv_);                                               \
    gload16(sv_ + 2048, dv_ + 2048);                                 \
  } while (0)

  // QK for one 16-row k-block: write raw scores into wave-private W chunk.
  // W chunk layout: row q'=(g<<4)+c (64B = 32 k), 16B blocks swizzled by q'&3.
#define QK_STEP(tr_) do {                                                       \
    const bf16x8 kf0 = ldfrag(sKc, ((tr_) << 4) + c, quad);                     \
    const bf16x8 kf1 = ldfrag(sKc, ((tr_) << 4) + c, 4 + quad);                 \
    _Pragma("unroll")                                                           \
    for (int g = 0; g < 2; ++g) {                                               \
      f32x4 acc = {0.f, 0.f, 0.f, 0.f};                                         \
      acc = MFMA16(kf0, qf[g][0], acc, 0, 0, 0);                                \
      acc = MFMA16(kf1, qf[g][1], acc, 0, 0, 0);                                \
      lac[g] += (exp2hw(acc[0]) + exp2hw(acc[1])) +                             \
                (exp2hw(acc[2]) + exp2hw(acc[3]));                              \
      const int q_ = (g << 4) + c;                                              \
      *(u64a*)((char*)wbase + (q_ << 6) +                                       \
               ((((((tr_) & 1) << 1) + (quad >> 1)) ^ (q_ & 3)) << 4) +         \
               ((quad & 1) << 3)) =                                             \
          (u64)cvtpk(acc[0], acc[1]) | ((u64)cvtpk(acc[2], acc[3]) << 32);      \
    }                                                                           \
  } while (0)

  // PV for one 32-wide k-half: mask applied by bitwise AND on raw scores.
#define PV_STEP(ks_, m0_, m1_) do {                                             \
    const u32x4 r0_ = __builtin_bit_cast(u32x4,                                 \
        *(const bf16x8a*)((const char*)wbase + (c << 6) +                       \
                          ((quad ^ (c & 3)) << 4)));                            \
    const u32x4 r1_ = __builtin_bit_cast(u32x4,                                 \
        *(const bf16x8a*)((const char*)wbase + ((16 + c) << 6) +                \
                          ((quad ^ (c & 3)) << 4)));                            \
    const bf16x8 w10 = __builtin_bit_cast(bf16x8, r0_ & (m0_));                 \
    const bf16x8 w20 = __builtin_bit_cast(bf16x8, (m0_) & 0x3F803F80u);         \
    const bf16x8 w11 = __builtin_bit_cast(bf16x8, r1_ & (m1_));                 \
    const bf16x8 w21 = __builtin_bit_cast(bf16x8, (m1_) & 0x3F803F80u);         \
    _Pragma("unroll")                                                           \
    for (int mt = 0; mt < 4; ++mt) {                                            \
      const bf16x8 av = ldfrag(sVc, (mt << 4) + c, ((ks_) << 2) + quad);        \
      accA0[mt] = MFMA16(av, w10, accA0[mt], 0, 0, 0);                          \
      accB0[mt] = MFMA16(av, w20, accB0[mt], 0, 0, 0);                          \
      accA1[mt] = MFMA16(av, w11, accA1[mt], 0, 0, 0);                          \
      accB1[mt] = MFMA16(av, w21, accB1[mt], 0, 0, 0);                          \
    }                                                                           \
  } while (0)

// compile-time memory fence: no memory op crosses (0 runtime instructions)
#define MEMFENCE asm volatile("" ::: "memory")

  STAGE(0, 0);

  for (int kt = 0; kt < 32; ++kt) {
    const int cur = kt & 1;
    const u16* sKc = sK[cur];
    const u16* sVc = sV[cur];
    // mask fragments for this k-tile (issued before next stage)
    const u32x4 m00 = *(const u32x4*)(mrow0 + (kt << 6));
    const u32x4 m01 = *(const u32x4*)(mrow0 + (kt << 6) + 32);
    const u32x4 m10 = *(const u32x4*)(mrow1 + (kt << 6));
    const u32x4 m11 = *(const u32x4*)(mrow1 + (kt << 6) + 32);
    if (kt < 31) {
      STAGE(kt + 1, cur ^ 1);
      // outstanding: 4 (tile kt) + 4 (mask) + 4 (tile kt+1) -> wait oldest 4
      asm volatile("s_waitcnt vmcnt(8)" ::: "memory");
    } else {
      asm volatile("s_waitcnt vmcnt(4)" ::: "memory");
    }
    __builtin_amdgcn_s_barrier();
    MEMFENCE;  // keep tile reads below the barrier

    QK_STEP(0);
    QK_STEP(1);
    MEMFENCE;  // W writes (QK) must precede W reads (PV)
    PV_STEP(0, m00, m10);
    MEMFENCE;  // W reads (PV ks=0) must precede W overwrites (QK tr2,3)
    QK_STEP(2);
    QK_STEP(3);
    MEMFENCE;
    PV_STEP(1, m01, m11);

    // drain this wave's LDS reads before anyone overwrites buf[cur] (kt+2 stage)
    asm volatile("s_waitcnt lgkmcnt(0)" ::: "memory");
    __builtin_amdgcn_s_barrier();
  }
#undef STAGE
#undef QK_STEP
#undef PV_STEP
#undef MEMFENCE

  // ---- lse per q-group (wave-local: quad butterflies only) ----
  const float ln2 = 0.6931471805599453f;
  float l0 = lac[0];
  l0 += __shfl_xor(l0, 16, 64);
  l0 += __shfl_xor(l0, 32, 64);
  const float c10 = 1e9f - __log2f(l0) * ln2;
  float l1 = lac[1];
  l1 += __shfl_xor(l1, 16, 64);
  l1 += __shfl_xor(l1, 32, 64);
  const float c11 = 1e9f - __log2f(l1) * ln2;

  // ---- epilogue: out[b][q][h*64+d] = ln2*A + c1*Bm - 1e9*Vsum ----
  const int b = bh >> 4, h = bh & 15;
#pragma unroll
  for (int mt = 0; mt < 4; ++mt) {
    const f32x4 vr = *(const f32x4*)(wsVs + (bh << 6) + (mt << 4) + (quad << 2));
    float4 o;
    o.x = ln2 * accA0[mt][0] + c10 * accB0[mt][0] - 1e9f * vr[0];
    o.y = ln2 * accA0[mt][1] + c10 * accB0[mt][1] - 1e9f * vr[1];
    o.z = ln2 * accA0[mt][2] + c10 * accB0[mt][2] - 1e9f * vr[2];
    o.w = ln2 * accA0[mt][3] + c10 * accB0[mt][3] - 1e9f * vr[3];
    const size_t off0 = ((size_t)b * S_LEN + (size_t)qrow0) * 1024 +
                        (h << 6) + (mt << 4) + (quad << 2);
    *(float4*)(gout + off0) = o;
    float4 p;
    p.x = ln2 * accA1[mt][0] + c11 * accB1[mt][0] - 1e9f * vr[0];
    p.y = ln2 * accA1[mt][1] + c11 * accB1[mt][1] - 1e9f * vr[1];
    p.z = ln2 * accA1[mt][2] + c11 * accB1[mt][2] - 1e9f * vr[2];
    p.w = ln2 * accA1[mt][3] + c11 * accB1[mt][3] - 1e9f * vr[3];
    *(float4*)(gout + off0 + (16 << 10)) = p;   // qrow0+16 -> +16*1024 floats
  }
}

extern "C" void kernel_launch(void* const* d_in, const int* in_sizes, int n_in,
                              void* d_out, int out_size, void* d_ws, size_t ws_size,
                              hipStream_t stream) {
  const float* q = (const float*)d_in[0];
  const float* k = (const float*)d_in[1];
  const float* v = (const float*)d_in[2];
  const int* mask = (const int*)d_in[3];
  (void)in_sizes; (void)n_in; (void)out_size; (void)ws_size;
  // workspace: wsK 16MB | wsV 16MB | wsM 8MB | wsVs 16KB  (~42MB total)
  u16* wsK = (u16*)d_ws;
  u16* wsV = wsK + ((size_t)64 << 17);
  u16* wsM = wsV + ((size_t)64 << 17);
  float* wsVs = (float*)(wsM + ((size_t)S_LEN * S_LEN));
  hipMemsetAsync(wsVs, 0, 64 * 64 * sizeof(float), stream);
  prep_kernel<<<dim3(3072), dim3(256), 0, stream>>>(k, v, mask, wsK, wsV, wsM, wsVs);
  attn_kernel<<<dim3(1024), dim3(256), 0, stream>>>(q, wsK, wsV, wsM, wsVs, (float*)d_out);
}

// Round 8
// 288.151 us; speedup vs baseline: 1.5292x; 1.5292x over previous
//
#include <hip/hip_runtime.h>

#define S_LEN 2048

typedef __attribute__((ext_vector_type(8))) short bf16x8;
typedef __attribute__((ext_vector_type(4))) float f32x4;
typedef __attribute__((ext_vector_type(4))) unsigned int u32x4;
typedef unsigned long long u64;
typedef unsigned int u32;
typedef unsigned short u16;

#define MFMA16 __builtin_amdgcn_mfma_f32_16x16x32_bf16

// single-instruction pack: a -> low16, b -> high16 (RNE)
__device__ __forceinline__ u32 cvtpk(float a, float b) {
  u32 r;
  asm("v_cvt_pk_bf16_f32 %0, %1, %2" : "=v"(r) : "v"(a), "v"(b));
  return r;
}
// raw hardware 2^x (avoid OCML wrapper ops around v_exp_f32)
__device__ __forceinline__ float exp2hw(float x) {
  float r;
  asm("v_exp_f32 %0, %1" : "=v"(r) : "v"(x));
  return r;
}

// 64x64 bf16 tile, 128B rows, 8 x 16B blocks/row, block swizzled by xor(row&7).
__device__ __forceinline__ u64* qkaddr(u16* dst, int row, int c4) {
  const int cb = c4 >> 1;
  return (u64*)((char*)dst + ((((row << 3) + (cb ^ (row & 7))) << 4) + ((c4 & 1) << 3)));
}
__device__ __forceinline__ bf16x8 ldfrag(const u16* base, int row, int blk) {
  const char* p = (const char*)base + (((row << 3) + (blk ^ (row & 7))) << 4);
  return *(const bf16x8*)p;
}

// async global->LDS, 16B per lane; LDS dst = wave-uniform base + lane*16.
__device__ __forceinline__ void gload16(const u16* g, u16* l) {
  __builtin_amdgcn_global_load_lds((const __attribute__((address_space(1))) void*)g,
                                   (__attribute__((address_space(3))) void*)l, 16, 0, 0);
}

// ---------------------------------------------------------------------------
// Pre-pass: one-time conversions into workspace.
//   blocks [0,2048):   (bh,kt) tiles: K -> bf16 swizzled chunks; V -> V^T bf16
//                      swizzled chunks via LDS transpose (coalesced both ways);
//                      Vsum partials reduced in LDS, one atomicAdd per (bh,d).
//   blocks [2048,3072): mask int32 -> u16 0xFFFF/0x0000, row-major [q][k]
// ---------------------------------------------------------------------------
__global__ __launch_bounds__(256) void prep_kernel(
    const float* __restrict__ gk, const float* __restrict__ gv,
    const int* __restrict__ gmask,
    u16* __restrict__ wsK, u16* __restrict__ wsV,
    u16* __restrict__ wsM, float* __restrict__ wsVs) {
  __shared__ float tile[64 * 65];   // V^T staged: tile[d*65 + k] (65-stride: bank-free)
  __shared__ float sred[2][256];    // Vsum partials
  const int bid = blockIdx.x, t = threadIdx.x;
  if (bid < 2048) {
    const int bh = bid >> 5, kt = bid & 31;
    const float* kg = gk + ((size_t)bh << 17) + ((size_t)kt << 12);
    const float* vg = gv + ((size_t)bh << 17) + ((size_t)kt << 12);
    u16* outK = wsK + ((size_t)bid << 12);
    u16* outV = wsV + ((size_t)bid << 12);
    const int r0 = t >> 4, c4 = t & 15;
#pragma unroll
    for (int i = 0; i < 4; ++i) {
      const int row = r0 + (i << 4);  // k index
      const float4 f = *(const float4*)(vg + (row << 6) + (c4 << 2));
      float* p = tile + row;
      p[((c4 << 2) + 0) * 65] = f.x;
      p[((c4 << 2) + 1) * 65] = f.y;
      p[((c4 << 2) + 2) * 65] = f.z;
      p[((c4 << 2) + 3) * 65] = f.w;
    }
#pragma unroll
    for (int i = 0; i < 2; ++i) {
      const int n = t + (i << 8);
      const int row = n >> 3, cb = (n & 7) ^ (row & 7);
      const float4 A = *(const float4*)(kg + (row << 6) + (cb << 3));
      const float4 B = *(const float4*)(kg + (row << 6) + (cb << 3) + 4);
      u32x4 w;
      w.x = cvtpk(A.x, A.y); w.y = cvtpk(A.z, A.w);
      w.z = cvtpk(B.x, B.y); w.w = cvtpk(B.z, B.w);
      *(u32x4*)(outK + ((size_t)n << 3)) = w;
    }
    __syncthreads();
#pragma unroll
    for (int i = 0; i < 2; ++i) {
      const int n = t + (i << 8);
      const int d = n >> 3, cb = (n & 7) ^ (d & 7);
      const float* src = tile + d * 65 + (cb << 3);
      float e[8], s = 0.f;
#pragma unroll
      for (int j = 0; j < 8; ++j) { e[j] = src[j]; s += e[j]; }
      sred[i][t] = s;
      u32x4 w;
      w.x = cvtpk(e[0], e[1]); w.y = cvtpk(e[2], e[3]);
      w.z = cvtpk(e[4], e[5]); w.w = cvtpk(e[6], e[7]);
      *(u32x4*)(outV + ((size_t)n << 3)) = w;
    }
    __syncthreads();
    if (t < 64) {
      const float* s8 = (t < 32) ? &sred[0][t << 3] : &sred[1][(t - 32) << 3];
      const float s = ((s8[0] + s8[1]) + (s8[2] + s8[3])) +
                      ((s8[4] + s8[5]) + (s8[6] + s8[7]));
      atomicAdd(&wsVs[(bh << 6) + t], s);
    }
  } else {
    const size_t base = ((size_t)(bid - 2048) << 12) + ((size_t)t << 4);
    int4 m[4];
#pragma unroll
    for (int i = 0; i < 4; ++i) m[i] = *(const int4*)(gmask + base + (i << 2));
    u32x4 w0, w1;
    w0.x = (m[0].x ? 0xFFFFu : 0u) | (m[0].y ? 0xFFFF0000u : 0u);
    w0.y = (m[0].z ? 0xFFFFu : 0u) | (m[0].w ? 0xFFFF0000u : 0u);
    w0.z = (m[1].x ? 0xFFFFu : 0u) | (m[1].y ? 0xFFFF0000u : 0u);
    w0.w = (m[1].z ? 0xFFFFu : 0u) | (m[1].w ? 0xFFFF0000u : 0u);
    w1.x = (m[2].x ? 0xFFFFu : 0u) | (m[2].y ? 0xFFFF0000u : 0u);
    w1.y = (m[2].z ? 0xFFFFu : 0u) | (m[2].w ? 0xFFFF0000u : 0u);
    w1.z = (m[3].x ? 0xFFFFu : 0u) | (m[3].y ? 0xFFFF0000u : 0u);
    w1.w = (m[3].z ? 0xFFFFu : 0u) | (m[3].w ? 0xFFFF0000u : 0u);
    *(u32x4*)(wsM + base) = w0;
    *(u32x4*)(wsM + base + 8) = w1;
  }
}

// ---------------------------------------------------------------------------
// Main kernel — PROVEN R2 STRUCTURE (attn 173us / total 295us, passed twice)
// + T5 s_setprio around MFMA clusters (only change this round).
// One block = one (b*h, 64-row q-tile); 2048 blocks, 4 waves.
// Single pass over K:  out = ln2*A + (1e9 - lse)*Bm - 1e9*Vsum
//   A  = sum_k mask*t*v   (t = s*log2e; Q pre-scaled by 0.125*log2e)
//   Bm = sum_k mask*v
//   lse = ln sum_k 2^t    (raw v_exp_f32 on MFMA output)
// K/V staged async via global_load_lds (pre-converted bf16, pre-swizzled),
// double-buffered with counted vmcnt(6) + raw s_barrier.
// W1 holds RAW packed scores; mask applied at PV by bitwise AND.
// NOTE: the 128-row/2-q-group restructure was abandoned after 4 rounds
// (R3/R5/R6/R7 fail NaN/Inf in codegen-correlated ways; R4 passes only with
// heavy spills). Do not re-attempt without a different decomposition.
// ---------------------------------------------------------------------------
__global__ __launch_bounds__(256, 4) void attn_kernel(
    const float* __restrict__ gq, const u16* __restrict__ wsK,
    const u16* __restrict__ wsV, const u16* __restrict__ wsM,
    const float* __restrict__ wsVs, float* __restrict__ gout) {
  __shared__ __align__(16) u16 sK[2][4096];   // 16 KB double-buffered K tile
  __shared__ __align__(16) u16 sV[2][4096];   // 16 KB double-buffered V^T tile
  __shared__ __align__(16) u16 sW1[4096];     // 8 KB: raw scores (Q staged here once)

  const int t = threadIdx.x;
  const int wv = t >> 6;
  const int lane = t & 63;
  const int c = lane & 15;
  const int quad = lane >> 4;
  const int r0 = t >> 4, c4 = t & 15;

  const int bx = blockIdx.x;
  const int bh = bx & 63;            // consecutive blocks share q0 -> mask L3 locality
  const int q0 = (bx >> 6) << 6;

  const float* qg = gq + ((size_t)bh << 17) + ((size_t)q0 << 6);
  const u16* srcK = wsK + ((size_t)bh << 17) + (t << 3);
  const u16* srcV = wsV + ((size_t)bh << 17) + (t << 3);
  const int qrow = q0 + (wv << 4) + c;
  const u16* mrow = wsM + ((size_t)qrow << 11) + (quad << 3);

  // Vsum fragments: d = 16*mt + 4*quad + j
  f32x4 vreg[4];
#pragma unroll
  for (int mt = 0; mt < 4; ++mt)
    vreg[mt] = *(const f32x4*)(wsVs + (bh << 6) + (mt << 4) + (quad << 2));

  // ---- stage Q once (scaled by 0.125*log2e) into sW1, swizzled ----
  const float qs = 0.1803368801111204f;  // 0.125 * log2(e)
#pragma unroll
  for (int i = 0; i < 4; ++i) {
    const int row = r0 + (i << 4);
    const float4 f = *(const float4*)(qg + ((size_t)row << 6) + (c4 << 2));
    const u32 lo = cvtpk(f.x * qs, f.y * qs);
    const u32 hi = cvtpk(f.z * qs, f.w * qs);
    *qkaddr(sW1, row, c4) = (u64)lo | ((u64)hi << 32);
  }
  __syncthreads();
  bf16x8 qf[2];
#pragma unroll
  for (int ks = 0; ks < 2; ++ks)
    qf[ks] = ldfrag(sW1, (wv << 4) + c, (ks << 2) + quad);
  // qf must be in regs before any wave's W1 writes (post first mid-barrier).
  asm volatile("s_waitcnt lgkmcnt(0)" ::: "memory");

  f32x4 accA[4], accB[4];
#pragma unroll
  for (int mt = 0; mt < 4; ++mt) {
    const f32x4 z = {0.f, 0.f, 0.f, 0.f};
    accA[mt] = z; accB[mt] = z;
  }
  float lacc = 0.f;

#define STAGE(kt_, buf_) do {                                        \
    const u16* sk_ = srcK + ((kt_) << 12);                           \
    const u16* sv_ = srcV + ((kt_) << 12);                           \
    u16* dk_ = &sK[buf_][wv << 9];                                   \
    u16* dv_ = &sV[buf_][wv << 9];                                   \
    gload16(sk_, dk_);                                               \
    gload16(sk_ + 2048, dk_ + 2048);                                 \
    gload16(sv_, dv_);                                               \
    gload16(sv_ + 2048, dv_ + 2048);                                 \
  } while (0)

  STAGE(0, 0);

  for (int kt = 0; kt < 32; ++kt) {
    const int cur = kt & 1;
    const u16* sKc = sK[cur];
    const u16* sVc = sV[cur];
    // mask fragments for this k-tile: issued BEFORE next stage so the
    // compiler's wait on them (PV) doesn't drain the in-flight stage loads.
    const u32x4 mm0 = *(const u32x4*)(mrow + ((size_t)kt << 6));
    const u32x4 mm1 = *(const u32x4*)(mrow + ((size_t)kt << 6) + 32);
    if (kt < 31) {
      STAGE(kt + 1, cur ^ 1);
      // outstanding: 4 (tile kt) + 2 (mask) + 4 (tile kt+1) -> wait oldest 4
      asm volatile("s_waitcnt vmcnt(6)" ::: "memory");
    } else {
      asm volatile("s_waitcnt vmcnt(2)" ::: "memory");
    }
    __builtin_amdgcn_s_barrier();
    asm volatile("" ::: "memory");  // keep tile reads below the barrier

    // ---- QK: S^T = K*Q^T (t-units), exp2 accumulation, raw-score W1 ----
#pragma unroll
    for (int tr = 0; tr < 4; ++tr) {
      f32x4 acc = {0.f, 0.f, 0.f, 0.f};
      __builtin_amdgcn_s_setprio(1);   // T5: favor MFMA-issuing wave
      acc = MFMA16(ldfrag(sKc, (tr << 4) + c, quad), qf[0], acc, 0, 0, 0);
      acc = MFMA16(ldfrag(sKc, (tr << 4) + c, 4 + quad), qf[1], acc, 0, 0, 0);
      __builtin_amdgcn_s_setprio(0);
      lacc += (exp2hw(acc[0]) + exp2hw(acc[1])) + (exp2hw(acc[2]) + exp2hw(acc[3]));
      *qkaddr(sW1, (wv << 4) + c, (tr << 2) + quad) =
          (u64)cvtpk(acc[0], acc[1]) | ((u64)cvtpk(acc[2], acc[3]) << 32);
    }
    // ---- PV: mask applied by AND; W wave-private -> no barrier needed ----
#pragma unroll
    for (int ks = 0; ks < 2; ++ks) {
      const u32x4 m = ks ? mm1 : mm0;
      const bf16x8 wr = ldfrag(sW1, (wv << 4) + c, (ks << 2) + quad);
      const u32x4 wraw = __builtin_bit_cast(u32x4, wr);
      const bf16x8 bw1 = __builtin_bit_cast(bf16x8, wraw & m);
      const bf16x8 bw2 = __builtin_bit_cast(bf16x8, m & 0x3F803F80u);
      __builtin_amdgcn_s_setprio(1);   // T5: favor MFMA-issuing wave
#pragma unroll
      for (int mt = 0; mt < 4; ++mt) {
        const bf16x8 av = ldfrag(sVc, (mt << 4) + c, (ks << 2) + quad);
        accA[mt] = MFMA16(av, bw1, accA[mt], 0, 0, 0);
        accB[mt] = MFMA16(av, bw2, accB[mt], 0, 0, 0);
      }
      __builtin_amdgcn_s_setprio(0);
    }
    // drain this wave's LDS reads before anyone overwrites buf[cur] (kt+2 stage)
    asm volatile("s_waitcnt lgkmcnt(0)" ::: "memory");
    __builtin_amdgcn_s_barrier();
  }
#undef STAGE

  // ---- lse (wave-local: quad butterflies only) ----
  float l = lacc;
  l += __shfl_xor(l, 16, 64);
  l += __shfl_xor(l, 32, 64);
  l = __log2f(l) * 0.6931471805599453f;
  const float c1 = 1e9f - l;

  // ---- epilogue: out[b][q][h*64+d] = ln2*A + c1*Bm - 1e9*Vsum ----
  const int b = bh >> 4, h = bh & 15;
  const float ln2 = 0.6931471805599453f;
#pragma unroll
  for (int mt = 0; mt < 4; ++mt) {
    float4 o;
    o.x = ln2 * accA[mt][0] + c1 * accB[mt][0] - 1e9f * vreg[mt][0];
    o.y = ln2 * accA[mt][1] + c1 * accB[mt][1] - 1e9f * vreg[mt][1];
    o.z = ln2 * accA[mt][2] + c1 * accB[mt][2] - 1e9f * vreg[mt][2];
    o.w = ln2 * accA[mt][3] + c1 * accB[mt][3] - 1e9f * vreg[mt][3];
    const size_t off = ((size_t)b * S_LEN + (size_t)qrow) * 1024 +
                       (h << 6) + (mt << 4) + (quad << 2);
    *(float4*)(gout + off) = o;
  }
}

extern "C" void kernel_launch(void* const* d_in, const int* in_sizes, int n_in,
                              void* d_out, int out_size, void* d_ws, size_t ws_size,
                              hipStream_t stream) {
  const float* q = (const float*)d_in[0];
  const float* k = (const float*)d_in[1];
  const float* v = (const float*)d_in[2];
  const int* mask = (const int*)d_in[3];
  (void)in_sizes; (void)n_in; (void)out_size; (void)ws_size;
  // workspace: wsK 16MB | wsV 16MB | wsM 8MB | wsVs 16KB  (~42MB total)
  u16* wsK = (u16*)d_ws;
  u16* wsV = wsK + ((size_t)64 << 17);
  u16* wsM = wsV + ((size_t)64 << 17);
  float* wsVs = (float*)(wsM + ((size_t)S_LEN * S_LEN));
  hipMemsetAsync(wsVs, 0, 64 * 64 * sizeof(float), stream);
  prep_kernel<<<dim3(3072), dim3(256), 0, stream>>>(k, v, mask, wsK, wsV, wsM, wsVs);
  attn_kernel<<<dim3(2048), dim3(256), 0, stream>>>(q, wsK, wsV, wsM, wsVs, (float*)d_out);
}

// Round 9
// 283.017 us; speedup vs baseline: 1.5570x; 1.0181x over previous
//
#include <hip/hip_runtime.h>

#define S_LEN 2048

typedef __attribute__((ext_vector_type(8))) short bf16x8;
typedef __attribute__((ext_vector_type(4))) float f32x4;
typedef __attribute__((ext_vector_type(4))) unsigned int u32x4;
typedef unsigned long long u64;
typedef unsigned int u32;
typedef unsigned short u16;

#define MFMA16 __builtin_amdgcn_mfma_f32_16x16x32_bf16

// single-instruction pack: a -> low16, b -> high16 (RNE)
__device__ __forceinline__ u32 cvtpk(float a, float b) {
  u32 r;
  asm("v_cvt_pk_bf16_f32 %0, %1, %2" : "=v"(r) : "v"(a), "v"(b));
  return r;
}
// raw hardware 2^x (avoid OCML wrapper ops around v_exp_f32)
__device__ __forceinline__ float exp2hw(float x) {
  float r;
  asm("v_exp_f32 %0, %1" : "=v"(r) : "v"(x));
  return r;
}

// 64x64 bf16 tile, 128B rows, 8 x 16B blocks/row, block swizzled by xor(row&7).
__device__ __forceinline__ u64* qkaddr(u16* dst, int row, int c4) {
  const int cb = c4 >> 1;
  return (u64*)((char*)dst + ((((row << 3) + (cb ^ (row & 7))) << 4) + ((c4 & 1) << 3)));
}
__device__ __forceinline__ bf16x8 ldfrag(const u16* base, int row, int blk) {
  const char* p = (const char*)base + (((row << 3) + (blk ^ (row & 7))) << 4);
  return *(const bf16x8*)p;
}

// async global->LDS, 16B per lane; LDS dst = wave-uniform base + lane*16.
__device__ __forceinline__ void gload16(const u16* g, u16* l) {
  __builtin_amdgcn_global_load_lds((const __attribute__((address_space(1))) void*)g,
                                   (__attribute__((address_space(3))) void*)l, 16, 0, 0);
}

// ---------------------------------------------------------------------------
// Pre-pass: one-time conversions into workspace (unchanged since R2).
// ---------------------------------------------------------------------------
__global__ __launch_bounds__(256) void prep_kernel(
    const float* __restrict__ gk, const float* __restrict__ gv,
    const int* __restrict__ gmask,
    u16* __restrict__ wsK, u16* __restrict__ wsV,
    u16* __restrict__ wsM, float* __restrict__ wsVs) {
  __shared__ float tile[64 * 65];   // V^T staged: tile[d*65 + k] (65-stride: bank-free)
  __shared__ float sred[2][256];    // Vsum partials
  const int bid = blockIdx.x, t = threadIdx.x;
  if (bid < 2048) {
    const int bh = bid >> 5, kt = bid & 31;
    const float* kg = gk + ((size_t)bh << 17) + ((size_t)kt << 12);
    const float* vg = gv + ((size_t)bh << 17) + ((size_t)kt << 12);
    u16* outK = wsK + ((size_t)bid << 12);
    u16* outV = wsV + ((size_t)bid << 12);
    const int r0 = t >> 4, c4 = t & 15;
#pragma unroll
    for (int i = 0; i < 4; ++i) {
      const int row = r0 + (i << 4);  // k index
      const float4 f = *(const float4*)(vg + (row << 6) + (c4 << 2));
      float* p = tile + row;
      p[((c4 << 2) + 0) * 65] = f.x;
      p[((c4 << 2) + 1) * 65] = f.y;
      p[((c4 << 2) + 2) * 65] = f.z;
      p[((c4 << 2) + 3) * 65] = f.w;
    }
#pragma unroll
    for (int i = 0; i < 2; ++i) {
      const int n = t + (i << 8);
      const int row = n >> 3, cb = (n & 7) ^ (row & 7);
      const float4 A = *(const float4*)(kg + (row << 6) + (cb << 3));
      const float4 B = *(const float4*)(kg + (row << 6) + (cb << 3) + 4);
      u32x4 w;
      w.x = cvtpk(A.x, A.y); w.y = cvtpk(A.z, A.w);
      w.z = cvtpk(B.x, B.y); w.w = cvtpk(B.z, B.w);
      *(u32x4*)(outK + ((size_t)n << 3)) = w;
    }
    __syncthreads();
#pragma unroll
    for (int i = 0; i < 2; ++i) {
      const int n = t + (i << 8);
      const int d = n >> 3, cb = (n & 7) ^ (d & 7);
      const float* src = tile + d * 65 + (cb << 3);
      float e[8], s = 0.f;
#pragma unroll
      for (int j = 0; j < 8; ++j) { e[j] = src[j]; s += e[j]; }
      sred[i][t] = s;
      u32x4 w;
      w.x = cvtpk(e[0], e[1]); w.y = cvtpk(e[2], e[3]);
      w.z = cvtpk(e[4], e[5]); w.w = cvtpk(e[6], e[7]);
      *(u32x4*)(outV + ((size_t)n << 3)) = w;
    }
    __syncthreads();
    if (t < 64) {
      const float* s8 = (t < 32) ? &sred[0][t << 3] : &sred[1][(t - 32) << 3];
      const float s = ((s8[0] + s8[1]) + (s8[2] + s8[3])) +
                      ((s8[4] + s8[5]) + (s8[6] + s8[7]));
      atomicAdd(&wsVs[(bh << 6) + t], s);
    }
  } else {
    const size_t base = ((size_t)(bid - 2048) << 12) + ((size_t)t << 4);
    int4 m[4];
#pragma unroll
    for (int i = 0; i < 4; ++i) m[i] = *(const int4*)(gmask + base + (i << 2));
    u32x4 w0, w1;
    w0.x = (m[0].x ? 0xFFFFu : 0u) | (m[0].y ? 0xFFFF0000u : 0u);
    w0.y = (m[0].z ? 0xFFFFu : 0u) | (m[0].w ? 0xFFFF0000u : 0u);
    w0.z = (m[1].x ? 0xFFFFu : 0u) | (m[1].y ? 0xFFFF0000u : 0u);
    w0.w = (m[1].z ? 0xFFFFu : 0u) | (m[1].w ? 0xFFFF0000u : 0u);
    w1.x = (m[2].x ? 0xFFFFu : 0u) | (m[2].y ? 0xFFFF0000u : 0u);
    w1.y = (m[2].z ? 0xFFFFu : 0u) | (m[2].w ? 0xFFFF0000u : 0u);
    w1.z = (m[3].x ? 0xFFFFu : 0u) | (m[3].y ? 0xFFFF0000u : 0u);
    w1.w = (m[3].z ? 0xFFFFu : 0u) | (m[3].w ? 0xFFFF0000u : 0u);
    *(u32x4*)(wsM + base) = w0;
    *(u32x4*)(wsM + base + 8) = w1;
  }
}

// ---------------------------------------------------------------------------
// Main kernel — PROVEN R2/R8 STRUCTURE + T5 setprio (R8, passed) + manual
// 2x kt-unroll (this round): buffer index `cur` becomes compile-time, so all
// LDS base addresses (sK/sV/sW1 reads+writes, 26 DS ops/kt) hoist out of the
// loop instead of being recomputed off a runtime `cur` every iteration.
// Ordering semantics byte-identical to R8 (same fences/barriers/vmcnt).
// One block = one (b*h, 64-row q-tile); 2048 blocks, 4 waves.
// out = ln2*A + (1e9 - lse)*Bm - 1e9*Vsum
// NOTE: the 128-row/2-q-group restructure was abandoned after 4 rounds
// (R3/R5/R6/R7 fail NaN/Inf codegen-correlated). Do not re-attempt.
// ---------------------------------------------------------------------------
__global__ __launch_bounds__(256, 4) void attn_kernel(
    const float* __restrict__ gq, const u16* __restrict__ wsK,
    const u16* __restrict__ wsV, const u16* __restrict__ wsM,
    const float* __restrict__ wsVs, float* __restrict__ gout) {
  __shared__ __align__(16) u16 sK[2][4096];   // 16 KB double-buffered K tile
  __shared__ __align__(16) u16 sV[2][4096];   // 16 KB double-buffered V^T tile
  __shared__ __align__(16) u16 sW1[4096];     // 8 KB: raw scores (Q staged here once)

  const int t = threadIdx.x;
  const int wv = t >> 6;
  const int lane = t & 63;
  const int c = lane & 15;
  const int quad = lane >> 4;
  const int r0 = t >> 4, c4 = t & 15;

  const int bx = blockIdx.x;
  const int bh = bx & 63;            // consecutive blocks share q0 -> mask L3 locality
  const int q0 = (bx >> 6) << 6;

  const float* qg = gq + ((size_t)bh << 17) + ((size_t)q0 << 6);
  const u16* srcK = wsK + ((size_t)bh << 17) + (t << 3);
  const u16* srcV = wsV + ((size_t)bh << 17) + (t << 3);
  const int qrow = q0 + (wv << 4) + c;
  const u16* mrow = wsM + ((size_t)qrow << 11) + (quad << 3);

  // Vsum fragments: d = 16*mt + 4*quad + j
  f32x4 vreg[4];
#pragma unroll
  for (int mt = 0; mt < 4; ++mt)
    vreg[mt] = *(const f32x4*)(wsVs + (bh << 6) + (mt << 4) + (quad << 2));

  // ---- stage Q once (scaled by 0.125*log2e) into sW1, swizzled ----
  const float qs = 0.1803368801111204f;  // 0.125 * log2(e)
#pragma unroll
  for (int i = 0; i < 4; ++i) {
    const int row = r0 + (i << 4);
    const float4 f = *(const float4*)(qg + ((size_t)row << 6) + (c4 << 2));
    const u32 lo = cvtpk(f.x * qs, f.y * qs);
    const u32 hi = cvtpk(f.z * qs, f.w * qs);
    *qkaddr(sW1, row, c4) = (u64)lo | ((u64)hi << 32);
  }
  __syncthreads();
  bf16x8 qf[2];
#pragma unroll
  for (int ks = 0; ks < 2; ++ks)
    qf[ks] = ldfrag(sW1, (wv << 4) + c, (ks << 2) + quad);
  // qf must be in regs before any wave's W1 writes (post first mid-barrier).
  asm volatile("s_waitcnt lgkmcnt(0)" ::: "memory");

  f32x4 accA[4], accB[4];
#pragma unroll
  for (int mt = 0; mt < 4; ++mt) {
    const f32x4 z = {0.f, 0.f, 0.f, 0.f};
    accA[mt] = z; accB[mt] = z;
  }
  float lacc = 0.f;

#define STAGE(kt_, buf_) do {                                        \
    const u16* sk_ = srcK + ((kt_) << 12);                           \
    const u16* sv_ = srcV + ((kt_) << 12);                           \
    u16* dk_ = &sK[buf_][wv << 9];                                   \
    u16* dv_ = &sV[buf_][wv << 9];                                   \
    gload16(sk_, dk_);                                               \
    gload16(sk_ + 2048, dk_ + 2048);                                 \
    gload16(sv_, dv_);                                               \
    gload16(sv_ + 2048, dv_ + 2048);                                 \
  } while (0)

  // One kt iteration; cur_ is a compile-time constant (0/1) so every LDS
  // address below is loop-invariant and hoists.
#define BODY(kt_, cur_) do {                                                     \
    const u16* sKc = sK[cur_];                                                   \
    const u16* sVc = sV[cur_];                                                   \
    const u32x4 mm0 = *(const u32x4*)(mrow + ((size_t)(kt_) << 6));              \
    const u32x4 mm1 = *(const u32x4*)(mrow + ((size_t)(kt_) << 6) + 32);         \
    if ((kt_) < 31) {                                                            \
      STAGE((kt_) + 1, (cur_) ^ 1);                                              \
      /* outstanding: 4 (tile kt) + 2 (mask) + 4 (tile kt+1) -> wait oldest 4 */ \
      asm volatile("s_waitcnt vmcnt(6)" ::: "memory");                           \
    } else {                                                                     \
      asm volatile("s_waitcnt vmcnt(2)" ::: "memory");                           \
    }                                                                            \
    __builtin_amdgcn_s_barrier();                                                \
    asm volatile("" ::: "memory"); /* keep tile reads below the barrier */       \
    /* QK: S^T = K*Q^T (t-units), exp2 accumulation, raw-score W1 */             \
    _Pragma("unroll")                                                            \
    for (int tr = 0; tr < 4; ++tr) {                                             \
      f32x4 acc = {0.f, 0.f, 0.f, 0.f};                                          \
      __builtin_amdgcn_s_setprio(1);                                             \
      acc = MFMA16(ldfrag(sKc, (tr << 4) + c, quad), qf[0], acc, 0, 0, 0);       \
      acc = MFMA16(ldfrag(sKc, (tr << 4) + c, 4 + quad), qf[1], acc, 0, 0, 0);   \
      __builtin_amdgcn_s_setprio(0);                                             \
      lacc += (exp2hw(acc[0]) + exp2hw(acc[1])) +                                \
              (exp2hw(acc[2]) + exp2hw(acc[3]));                                 \
      *qkaddr(sW1, (wv << 4) + c, (tr << 2) + quad) =                            \
          (u64)cvtpk(acc[0], acc[1]) | ((u64)cvtpk(acc[2], acc[3]) << 32);       \
    }                                                                            \
    /* PV: mask applied by AND; W wave-private -> no barrier needed */           \
    _Pragma("unroll")                                                            \
    for (int ks = 0; ks < 2; ++ks) {                                             \
      const u32x4 m = ks ? mm1 : mm0;                                            \
      const bf16x8 wr = ldfrag(sW1, (wv << 4) + c, (ks << 2) + quad);            \
      const u32x4 wraw = __builtin_bit_cast(u32x4, wr);                          \
      const bf16x8 bw1 = __builtin_bit_cast(bf16x8, wraw & m);                   \
      const bf16x8 bw2 = __builtin_bit_cast(bf16x8, m & 0x3F803F80u);            \
      __builtin_amdgcn_s_setprio(1);                                             \
      _Pragma("unroll")                                                          \
      for (int mt = 0; mt < 4; ++mt) {                                           \
        const bf16x8 av = ldfrag(sVc, (mt << 4) + c, (ks << 2) + quad);          \
        accA[mt] = MFMA16(av, bw1, accA[mt], 0, 0, 0);                           \
        accB[mt] = MFMA16(av, bw2, accB[mt], 0, 0, 0);                           \
      }                                                                          \
      __builtin_amdgcn_s_setprio(0);                                             \
    }                                                                            \
    /* drain this wave's LDS reads before buf[cur] is overwritten (kt+2) */      \
    asm volatile("s_waitcnt lgkmcnt(0)" ::: "memory");                           \
    __builtin_amdgcn_s_barrier();                                                \
  } while (0)

  STAGE(0, 0);

  for (int kt = 0; kt < 32; kt += 2) {
    BODY(kt, 0);
    BODY(kt + 1, 1);
  }
#undef STAGE
#undef BODY

  // ---- lse (wave-local: quad butterflies only) ----
  float l = lacc;
  l += __shfl_xor(l, 16, 64);
  l += __shfl_xor(l, 32, 64);
  l = __log2f(l) * 0.6931471805599453f;
  const float c1 = 1e9f - l;

  // ---- epilogue: out[b][q][h*64+d] = ln2*A + c1*Bm - 1e9*Vsum ----
  const int b = bh >> 4, h = bh & 15;
  const float ln2 = 0.6931471805599453f;
#pragma unroll
  for (int mt = 0; mt < 4; ++mt) {
    float4 o;
    o.x = ln2 * accA[mt][0] + c1 * accB[mt][0] - 1e9f * vreg[mt][0];
    o.y = ln2 * accA[mt][1] + c1 * accB[mt][1] - 1e9f * vreg[mt][1];
    o.z = ln2 * accA[mt][2] + c1 * accB[mt][2] - 1e9f * vreg[mt][2];
    o.w = ln2 * accA[mt][3] + c1 * accB[mt][3] - 1e9f * vreg[mt][3];
    const size_t off = ((size_t)b * S_LEN + (size_t)qrow) * 1024 +
                       (h << 6) + (mt << 4) + (quad << 2);
    *(float4*)(gout + off) = o;
  }
}

extern "C" void kernel_launch(void* const* d_in, const int* in_sizes, int n_in,
                              void* d_out, int out_size, void* d_ws, size_t ws_size,
                              hipStream_t stream) {
  const float* q = (const float*)d_in[0];
  const float* k = (const float*)d_in[1];
  const float* v = (const float*)d_in[2];
  const int* mask = (const int*)d_in[3];
  (void)in_sizes; (void)n_in; (void)out_size; (void)ws_size;
  // workspace: wsK 16MB | wsV 16MB | wsM 8MB | wsVs 16KB  (~42MB total)
  u16* wsK = (u16*)d_ws;
  u16* wsV = wsK + ((size_t)64 << 17);
  u16* wsM = wsV + ((size_t)64 << 17);
  float* wsVs = (float*)(wsM + ((size_t)S_LEN * S_LEN));
  hipMemsetAsync(wsVs, 0, 64 * 64 * sizeof(float), stream);
  prep_kernel<<<dim3(3072), dim3(256), 0, stream>>>(k, v, mask, wsK, wsV, wsM, wsVs);
  attn_kernel<<<dim3(2048), dim3(256), 0, stream>>>(q, wsK, wsV, wsM, wsVs, (float*)d_out);
}